// Round 7
// baseline (456.752 us; speedup 1.0000x reference)
//
#include <hip/hip_runtime.h>

typedef __attribute__((ext_vector_type(8))) short bf16x8;
typedef __attribute__((ext_vector_type(8))) unsigned short u16x8;
typedef __attribute__((ext_vector_type(4))) float f32x4;
typedef unsigned int u32;

#define CI 64
#define CO 128
#define HH 256
#define WW 256
#define HP 258
#define WP 258
#define SLIDE 576.0f

__device__ __forceinline__ unsigned short f2bf(float f) {
  union { float f; unsigned int u; } c; c.f = f;
  unsigned int u = c.u;
  return (unsigned short)((u + 0x7FFFu + ((u >> 16) & 1u)) >> 16);
}
__device__ __forceinline__ float bf2f(unsigned short h) {
  union { unsigned int u; float f; } c; c.u = ((unsigned int)h) << 16;
  return c.f;
}

// K_xm: blocks <8192: xm = bf16(x*mask) -> padded NHWC via LDS transpose; msum = sum_ci mask.
//       blocks >=8192: W -> Wb [kh][kw][co][ci] bf16 transpose, and xm border zeroing.
__global__ __launch_bounds__(256) void k_xm(const f32x4* __restrict__ x4,
                                            const f32x4* __restrict__ m4,
                                            unsigned short* __restrict__ xm,
                                            float4* __restrict__ msum4,
                                            const float* __restrict__ W,
                                            unsigned short* __restrict__ Wb) {
  __shared__ __align__(16) float tile[64 * 64 + 256];   // 16 KB tile + 1 KB reduce
  int b = blockIdx.x;
  int t = threadIdx.x;
  if (b >= 8192) {
    int blk = b - 8192;
    if (blk < 288) {
      int i = blk * 256 + t;            // exactly 9*128*64 = 73728
      int ci = i & 63, co = (i >> 6) & 127, tap = i >> 13;
      int kh = tap / 3, kw = tap - 3 * (tap / 3);
      Wb[i] = f2bf(W[((co * CI + ci) * 3 + kh) * 3 + kw]);
    } else {
      int i = (blk - 288) * 256 + t;    // 8 n * 1028 border pixels
      if (i >= 8 * 1028) return;
      int n = i / 1028, p = i - n * 1028;
      int hh, wp;
      if (p < 258) { hh = 0; wp = p; }
      else if (p < 516) { hh = 257; wp = p - 258; }
      else { int q = p - 516; hh = 1 + (q >> 1); wp = (q & 1) * 257; }
      u16x8 z = {0, 0, 0, 0, 0, 0, 0, 0};
      unsigned short* d = xm + (((size_t)n * HP + hh) * WP + wp) * CI;
#pragma unroll
      for (int k = 0; k < 8; ++k) *(u16x8*)(d + k * 8) = z;
    }
    return;
  }
  int wt = b & 3, h = (b >> 2) & 255, n = b >> 10;
  int w0 = wt * 64;
  int p4 = t & 15, chg = t >> 4;                         // px-quad, ch-group(4)
  size_t base = (size_t)n * CI * 16384 + (size_t)h * 64 + (w0 >> 2) + p4;
  float msx = 0.f, msy = 0.f, msz = 0.f, msw = 0.f;
#pragma unroll
  for (int j = 0; j < 4; ++j) {
    int ch = chg * 4 + j;
    size_t o = base + (size_t)ch * 16384;
    f32x4 xv = __builtin_nontemporal_load(&x4[o]);
    f32x4 mv = __builtin_nontemporal_load(&m4[o]);
    msx += mv.x; msy += mv.y; msz += mv.z; msw += mv.w;
    f32x4 pr = xv * mv;
    int kk = (ch >> 3) & 3;                              // XOR key (bits 2-3 of px idx)
    *(f32x4*)&tile[ch * 64 + ((p4 * 4) ^ (kk << 2))] = pr;
  }
  msx += __shfl_xor(msx, 16); msy += __shfl_xor(msy, 16);
  msz += __shfl_xor(msz, 16); msw += __shfl_xor(msw, 16);
  msx += __shfl_xor(msx, 32); msy += __shfl_xor(msy, 32);
  msz += __shfl_xor(msz, 32); msw += __shfl_xor(msw, 32);
  int wave = t >> 6, lane = t & 63;
  float4* red = (float4*)&tile[4096];
  if (lane < 16) red[wave * 16 + lane] = make_float4(msx, msy, msz, msw);
  __syncthreads();
  size_t dstb = (((size_t)n * HP + h + 1) * WP + (w0 + 1)) * CI;
#pragma unroll
  for (int iter = 0; iter < 2; ++iter) {
    int c = iter * 256 + t;
    int px = c >> 3, cg = c & 7;
    u16x8 v;
#pragma unroll
    for (int e = 0; e < 8; ++e) {
      int ch = cg * 8 + e;
      int kk = (ch >> 3) & 3;
      v[e] = f2bf(tile[ch * 64 + (px ^ (kk << 2))]);
    }
    *(u16x8*)(xm + dstb + (size_t)px * CI + cg * 8) = v;
  }
  if (t < 16) {
    float4 a = red[t], b2 = red[16 + t], c2 = red[32 + t], d2 = red[48 + t];
    float4 s;
    s.x = a.x + b2.x + c2.x + d2.x; s.y = a.y + b2.y + c2.y + d2.y;
    s.z = a.z + b2.z + c2.z + d2.z; s.w = a.w + b2.w + c2.w + d2.w;
    msum4[(size_t)n * 16384 + (size_t)h * 64 + (w0 >> 2) + t] = s;
  }
}

// K_conv: implicit-GEMM 3x3 conv, 128px x 128co per block, 4 waves, 16x16x32 bf16 MFMA.
// (reverted to the proven round-5 structure)
__global__ __launch_bounds__(256) void k_conv(
    const unsigned short* __restrict__ xm, const unsigned short* __restrict__ Wb,
    const float* __restrict__ msum, const float* __restrict__ bias,
    unsigned short* __restrict__ blob, float* __restrict__ psum, float* __restrict__ psq) {
  __shared__ __align__(16) char lds[51472];  // 49920 staging (reused as tile) + lr/lu/cs
  int b = blockIdx.x;
  // XCD swizzle: each XCD owns one image n, h-contiguous -> row reuse in its L2
  int work = (b & 7) * 512 + (b >> 3);
  int wt = work & 1, h = (work >> 1) & 255, n = work >> 9;
  int w0 = wt * 128;
  int t = threadIdx.x;
  int lane = t & 63, wave = t >> 6;
  float* lr = (float*)(lds + 49920);   // ratio*clip per px (128)
  float* lu = (float*)(lds + 50432);   // clip(update) per px (128)
  float* cs = (float*)(lds + 50944);   // column sums (130)
  // stage 3 padded rows x 130 px x 64ch = 3120 16B chunks, swizzled source addr
#pragma unroll
  for (int iter = 0; iter < 12; ++iter) {
    int c = iter * 256 + t;
    int r = (c >= 2080) ? 2 : (c >= 1040 ? 1 : 0);
    int cc = c - r * 1040;
    int wslot = cc >> 3, sub = cc & 7;
    int srcc = (wslot << 3) + (sub ^ (wslot & 7));
    const unsigned short* g = xm + (((size_t)n * HP + h + r) * WP + w0) * CI + (size_t)srcc * 8;
    u32 ldsoff = (u32)(r * 16640 + (((iter * 256 + (wave << 6)) - r * 1040) << 4));
    __builtin_amdgcn_global_load_lds((const __attribute__((address_space(1))) u32*)g,
        (__attribute__((address_space(3))) u32*)(void*)(lds + ldsoff), 16, 0, 0);
  }
  if (t < 48) {   // tail: chunks 3072..3119 (all r=2)
    int c = 3072 + t;
    int cc = c - 2080;
    int wslot = cc >> 3, sub = cc & 7;
    int srcc = (wslot << 3) + (sub ^ (wslot & 7));
    const unsigned short* g = xm + (((size_t)n * HP + h + 2) * WP + w0) * CI + (size_t)srcc * 8;
    u32 ldsoff = (u32)(2 * 16640 + ((3072 - 2080) << 4));
    __builtin_amdgcn_global_load_lds((const __attribute__((address_space(1))) u32*)g,
        (__attribute__((address_space(3))) u32*)(void*)(lds + ldsoff), 16, 0, 0);
  }
  // column sums of mask-count for this strip (w0-1 .. w0+128)
  if (t < 130) {
    int w = w0 - 1 + t;
    float s = 0.f;
    if ((unsigned)w < 256u) {
      const float* mcol = msum + (size_t)n * 65536 + w;
      if (h >= 1) s += mcol[(h - 1) * 256];
      s += mcol[h * 256];
      if (h < 255) s += mcol[(h + 1) * 256];
    }
    cs[t] = s;
  }
  __syncthreads();
  if (t < 128) {
    float s = cs[t] + cs[t + 1] + cs[t + 2];
    float uc = fminf(s, 1.0f);
    lu[t] = uc;
    lr[t] = SLIDE / (s + 1e-6f) * uc;
  }

  int wm = wave >> 1, wn = wave & 1;
  int l15 = lane & 15, l4 = lane >> 4;
  f32x4 zero = {0.f, 0.f, 0.f, 0.f};
  f32x4 acc[4][4];
#pragma unroll
  for (int i = 0; i < 4; ++i)
#pragma unroll
    for (int j = 0; j < 4; ++j) acc[i][j] = zero;

#pragma unroll
  for (int kh = 0; kh < 3; ++kh) {
#pragma unroll
    for (int kw = 0; kw < 3; ++kw) {
      const unsigned short* wtap = Wb + ((kh * 3 + kw) * CO + wn * 64) * CI;
#pragma unroll
      for (int ks = 0; ks < 2; ++ks) {
        bf16x8 af[4], bfr[4];
#pragma unroll
        for (int mf = 0; mf < 4; ++mf) {
          int wslot = wm * 64 + mf * 16 + l15 + kw;
          int baddr = (((kh * 130 + wslot) << 7) + ks * 64 + l4 * 16) ^ ((wslot & 7) << 4);
          af[mf] = *(const bf16x8*)(lds + baddr);
        }
#pragma unroll
        for (int nf = 0; nf < 4; ++nf)
          bfr[nf] = *(const bf16x8*)(wtap + (nf * 16 + l15) * CI + ks * 32 + l4 * 8);
#pragma unroll
        for (int mf = 0; mf < 4; ++mf)
#pragma unroll
          for (int nf = 0; nf < 4; ++nf)
            acc[mf][nf] = __builtin_amdgcn_mfma_f32_16x16x32_bf16(af[mf], bfr[nf], acc[mf][nf], 0, 0, 0);
      }
    }
  }
  __syncthreads();   // staging area free; reuse as co-major output tile [co][128px]

  float bv[4];
#pragma unroll
  for (int nf = 0; nf < 4; ++nf) bv[nf] = bias[wn * 64 + nf * 16 + l15];
  float rs_s[4] = {0.f, 0.f, 0.f, 0.f}, rq_s[4] = {0.f, 0.f, 0.f, 0.f};
  int px0 = wm * 64 + l4 * 4;    // r2 packs 4 consecutive px
#pragma unroll
  for (int mf = 0; mf < 4; ++mf) {
    int pxb = px0 + mf * 16;
    float rs0 = lr[pxb], rs1 = lr[pxb + 1], rs2 = lr[pxb + 2], rs3 = lr[pxb + 3];
    float uc0 = lu[pxb], uc1 = lu[pxb + 1], uc2 = lu[pxb + 2], uc3 = lu[pxb + 3];
#pragma unroll
    for (int nf = 0; nf < 4; ++nf) {
      int co = wn * 64 + nf * 16 + l15;
      float v0 = acc[mf][nf][0] * rs0 + bv[nf] * uc0;
      float v1 = acc[mf][nf][1] * rs1 + bv[nf] * uc1;
      float v2 = acc[mf][nf][2] * rs2 + bv[nf] * uc2;
      float v3 = acc[mf][nf][3] * rs3 + bv[nf] * uc3;
      unsigned short h0 = f2bf(v0), h1 = f2bf(v1), h2 = f2bf(v2), h3 = f2bf(v3);
      float w0f = bf2f(h0), w1f = bf2f(h1), w2f = bf2f(h2), w3f = bf2f(h3);
      rs_s[nf] += w0f + w1f + w2f + w3f;
      rq_s[nf] += w0f * w0f + w1f * w1f + w2f * w2f + w3f * w3f;
      u32 lo = (u32)h0 | ((u32)h1 << 16);
      u32 hi = (u32)h2 | ((u32)h3 << 16);
      *(uint2*)(lds + co * 272 + pxb * 2) = make_uint2(lo, hi);
    }
  }
  float* sred = (float*)(lds + 34816);   // 512 floats (above tile's 34816 B)
#pragma unroll
  for (int nf = 0; nf < 4; ++nf) {
    float s = rs_s[nf], q = rq_s[nf];
    s += __shfl_xor(s, 16); s += __shfl_xor(s, 32);
    q += __shfl_xor(q, 16); q += __shfl_xor(q, 32);
    if (l4 == 0) {
      sred[(wave * 4 + nf) * 16 + l15] = s;
      sred[256 + (wave * 4 + nf) * 16 + l15] = q;
    }
  }
  __syncthreads();
  // blob store: NCHW bf16, 256B contiguous per 16 lanes
  int pixrow = (n * CO) << 16;
#pragma unroll
  for (int iter = 0; iter < 8; ++iter) {
    int i = iter * 256 + t;
    int co = i >> 4, oct = i & 15;
    u16x8 v = *(const u16x8*)(lds + co * 272 + oct * 16);
    *(u16x8*)(blob + (size_t)(pixrow + (co << 16) + (h << 8) + w0 + oct * 8)) = v;
  }
  int co = t & 127;
  int wn2 = co >> 6, nf2 = (co >> 4) & 3, cc2 = co & 15;
  float a0 = sred[(wn2 * 4 + nf2) * 16 + cc2] + sred[((2 + wn2) * 4 + nf2) * 16 + cc2];
  float a1 = sred[256 + (wn2 * 4 + nf2) * 16 + cc2] + sred[256 + ((2 + wn2) * 4 + nf2) * 16 + cc2];
  if (t < 128) psum[(size_t)b * 128 + co] = a0;
  else         psq[(size_t)b * 128 + co]  = a1;
}

// K_bnstats: reduce partials -> bn scale/shift
__global__ void k_bnstats(const float* __restrict__ psum, const float* __restrict__ psq,
                          const float* __restrict__ gamma, const float* __restrict__ beta,
                          float* __restrict__ bn_scale, float* __restrict__ bn_shift) {
  int co = blockIdx.x;
  int t = threadIdx.x;
  float s = 0.f, q = 0.f;
  for (int i = t; i < 4096; i += 256) {
    s += psum[(size_t)i * 128 + co];
    q += psq[(size_t)i * 128 + co];
  }
#pragma unroll
  for (int o = 1; o < 64; o <<= 1) { s += __shfl_xor(s, o); q += __shfl_xor(q, o); }
  __shared__ float red[8];
  int wv = t >> 6, ln = t & 63;
  if (ln == 0) { red[wv] = s; red[4 + wv] = q; }
  __syncthreads();
  if (t == 0) {
    s = red[0] + red[1] + red[2] + red[3];
    q = red[4] + red[5] + red[6] + red[7];
    const float inv = 1.0f / 524288.0f;
    float mean = s * inv;
    float var = q * inv - mean * mean;
    float sc = gamma[co] * rsqrtf(var + 1e-5f);
    bn_scale[co] = sc;
    bn_shift[co] = beta[co] - mean * sc;
  }
}

// K_out: pure streaming. Block = (n,h) row: updc row from msum in LDS, then
// blob (NCHW bf16) -> BN+ReLU -> out (f32 NCHW, nt) and upd broadcast (nt).
__global__ __launch_bounds__(256) void k_out(const unsigned short* __restrict__ blob,
                                             const float* __restrict__ msum,
                                             const float* __restrict__ bn_scale,
                                             const float* __restrict__ bn_shift,
                                             float* __restrict__ out,
                                             float* __restrict__ upd) {
  __shared__ float lu[256];
  __shared__ float cs[258];
  __shared__ float lsc[128], lsh[128];
  int b = blockIdx.x;
  int h = b & 255, n = b >> 8;
  int t = threadIdx.x;
  if (t < 258) {
    int w = t - 1;
    float s = 0.f;
    if ((unsigned)w < 256u) {
      const float* mcol = msum + (size_t)n * 65536 + w;
      if (h >= 1) s += mcol[(h - 1) * 256];
      s += mcol[h * 256];
      if (h < 255) s += mcol[(h + 1) * 256];
    }
    cs[t] = s;
  }
  if (t < 128) { lsc[t] = bn_scale[t]; lsh[t] = bn_shift[t]; }
  __syncthreads();
  if (t < 256) lu[t] = fminf(cs[t] + cs[t + 1] + cs[t + 2], 1.0f);
  __syncthreads();
  size_t rowbase = ((size_t)(n * CO) << 16) + (h << 8);
#pragma unroll
  for (int iter = 0; iter < 16; ++iter) {
    int i = iter * 256 + t;               // 4096 = 128 c * 32 oct(8px)
    int c = i >> 5, q8 = i & 31;
    size_t off = rowbase + ((size_t)c << 16) + q8 * 8;
    u16x8 raw = *(const u16x8*)(blob + off);
    float sc = lsc[c], sh = lsh[c];
    f32x4 v0, v1;
    v0.x = fmaxf(bf2f((unsigned short)raw[0]) * sc + sh, 0.f);
    v0.y = fmaxf(bf2f((unsigned short)raw[1]) * sc + sh, 0.f);
    v0.z = fmaxf(bf2f((unsigned short)raw[2]) * sc + sh, 0.f);
    v0.w = fmaxf(bf2f((unsigned short)raw[3]) * sc + sh, 0.f);
    v1.x = fmaxf(bf2f((unsigned short)raw[4]) * sc + sh, 0.f);
    v1.y = fmaxf(bf2f((unsigned short)raw[5]) * sc + sh, 0.f);
    v1.z = fmaxf(bf2f((unsigned short)raw[6]) * sc + sh, 0.f);
    v1.w = fmaxf(bf2f((unsigned short)raw[7]) * sc + sh, 0.f);
    __builtin_nontemporal_store(v0, (f32x4*)(out + off));
    __builtin_nontemporal_store(v1, (f32x4*)(out + off + 4));
    f32x4 u0 = *(const f32x4*)&lu[q8 * 8];
    f32x4 u1 = *(const f32x4*)&lu[q8 * 8 + 4];
    __builtin_nontemporal_store(u0, (f32x4*)(upd + off));
    __builtin_nontemporal_store(u1, (f32x4*)(upd + off + 4));
  }
}

extern "C" void kernel_launch(void* const* d_in, const int* in_sizes, int n_in,
                              void* d_out, int out_size, void* d_ws, size_t ws_size,
                              hipStream_t stream) {
  (void)in_sizes; (void)n_in; (void)out_size; (void)ws_size;
  const float* x     = (const float*)d_in[0];
  const float* mask  = (const float*)d_in[1];
  const float* W     = (const float*)d_in[2];
  const float* bias  = (const float*)d_in[3];
  const float* gamma = (const float*)d_in[4];
  const float* beta  = (const float*)d_in[5];

  float* out = (float*)d_out;                // output 0: 64M f32
  float* upd_out = out + 67108864;           // output 1: 64M f32

  char* wsb = (char*)d_ws;
  unsigned short* Wb = (unsigned short*)wsb;                    // 147,456 B
  float* msum     = (float*)(wsb + (2u << 20));                 // 2 MB
  float* bn_scale = (float*)(wsb + (8u << 20));                 // 512 B
  float* bn_shift = bn_scale + 128;
  float* part_sum = (float*)(wsb + (9u << 20));                 // 2 MB
  float* part_sq  = (float*)(wsb + (11u << 20));                // 2 MB
  unsigned short* xm   = (unsigned short*)(wsb + (16u << 20));  // 65 MB padded NHWC bf16
  unsigned short* blob = (unsigned short*)(wsb + (96u << 20));  // 128 MB NCHW bf16

  k_xm<<<8513, 256, 0, stream>>>((const f32x4*)x, (const f32x4*)mask, xm,
                                 (float4*)msum, W, Wb);
  k_conv<<<4096, 256, 0, stream>>>(xm, Wb, msum, bias, blob, part_sum, part_sq);
  k_bnstats<<<128, 256, 0, stream>>>(part_sum, part_sq, gamma, beta, bn_scale, bn_shift);
  k_out<<<2048, 256, 0, stream>>>(blob, msum, bn_scale, bn_shift, out, upd_out);
}

// Round 8
// 343.464 us; speedup vs baseline: 1.3298x; 1.3298x over previous
//
#include <hip/hip_runtime.h>

typedef __attribute__((ext_vector_type(8))) short bf16x8;
typedef __attribute__((ext_vector_type(8))) unsigned short u16x8;
typedef __attribute__((ext_vector_type(4))) float f32x4;
typedef unsigned int u32;

#define CI 64
#define CO 128
#define HH 256
#define WW 256
#define HP 258
#define WP 258
#define SLIDE 576.0f

__device__ __forceinline__ unsigned short f2bf(float f) {
  union { float f; unsigned int u; } c; c.f = f;
  unsigned int u = c.u;
  return (unsigned short)((u + 0x7FFFu + ((u >> 16) & 1u)) >> 16);
}
__device__ __forceinline__ float bf2f(unsigned short h) {
  union { unsigned int u; float f; } c; c.u = ((unsigned int)h) << 16;
  return c.f;
}

// K_xm: blocks <8192: xm = bf16(x*mask) -> padded NHWC via LDS transpose; msum = sum_ci mask.
//       blocks >=8192: W -> Wb [kh][kw][co][ci] bf16 transpose, and xm border zeroing.
__global__ __launch_bounds__(256) void k_xm(const f32x4* __restrict__ x4,
                                            const f32x4* __restrict__ m4,
                                            unsigned short* __restrict__ xm,
                                            float4* __restrict__ msum4,
                                            const float* __restrict__ W,
                                            unsigned short* __restrict__ Wb) {
  __shared__ __align__(16) float tile[64 * 64 + 256];   // 16 KB tile + 1 KB reduce
  int b = blockIdx.x;
  int t = threadIdx.x;
  if (b >= 8192) {
    int blk = b - 8192;
    if (blk < 288) {
      int i = blk * 256 + t;            // exactly 9*128*64 = 73728
      int ci = i & 63, co = (i >> 6) & 127, tap = i >> 13;
      int kh = tap / 3, kw = tap - 3 * (tap / 3);
      Wb[i] = f2bf(W[((co * CI + ci) * 3 + kh) * 3 + kw]);
    } else {
      int i = (blk - 288) * 256 + t;    // 8 n * 1028 border pixels
      if (i >= 8 * 1028) return;
      int n = i / 1028, p = i - n * 1028;
      int hh, wp;
      if (p < 258) { hh = 0; wp = p; }
      else if (p < 516) { hh = 257; wp = p - 258; }
      else { int q = p - 516; hh = 1 + (q >> 1); wp = (q & 1) * 257; }
      u16x8 z = {0, 0, 0, 0, 0, 0, 0, 0};
      unsigned short* d = xm + (((size_t)n * HP + hh) * WP + wp) * CI;
#pragma unroll
      for (int k = 0; k < 8; ++k) *(u16x8*)(d + k * 8) = z;
    }
    return;
  }
  int wt = b & 3, h = (b >> 2) & 255, n = b >> 10;
  int w0 = wt * 64;
  int p4 = t & 15, chg = t >> 4;                         // px-quad, ch-group(4)
  size_t base = (size_t)n * CI * 16384 + (size_t)h * 64 + (w0 >> 2) + p4;
  float msx = 0.f, msy = 0.f, msz = 0.f, msw = 0.f;
#pragma unroll
  for (int j = 0; j < 4; ++j) {
    int ch = chg * 4 + j;
    size_t o = base + (size_t)ch * 16384;
    f32x4 xv = __builtin_nontemporal_load(&x4[o]);
    f32x4 mv = __builtin_nontemporal_load(&m4[o]);
    msx += mv.x; msy += mv.y; msz += mv.z; msw += mv.w;
    f32x4 pr = xv * mv;
    int kk = (ch >> 3) & 3;                              // XOR key (bits 2-3 of px idx)
    *(f32x4*)&tile[ch * 64 + ((p4 * 4) ^ (kk << 2))] = pr;
  }
  msx += __shfl_xor(msx, 16); msy += __shfl_xor(msy, 16);
  msz += __shfl_xor(msz, 16); msw += __shfl_xor(msw, 16);
  msx += __shfl_xor(msx, 32); msy += __shfl_xor(msy, 32);
  msz += __shfl_xor(msz, 32); msw += __shfl_xor(msw, 32);
  int wave = t >> 6, lane = t & 63;
  float4* red = (float4*)&tile[4096];
  if (lane < 16) red[wave * 16 + lane] = make_float4(msx, msy, msz, msw);
  __syncthreads();
  size_t dstb = (((size_t)n * HP + h + 1) * WP + (w0 + 1)) * CI;
#pragma unroll
  for (int iter = 0; iter < 2; ++iter) {
    int c = iter * 256 + t;
    int px = c >> 3, cg = c & 7;
    u16x8 v;
#pragma unroll
    for (int e = 0; e < 8; ++e) {
      int ch = cg * 8 + e;
      int kk = (ch >> 3) & 3;
      v[e] = f2bf(tile[ch * 64 + (px ^ (kk << 2))]);
    }
    *(u16x8*)(xm + dstb + (size_t)px * CI + cg * 8) = v;
  }
  if (t < 16) {
    float4 a = red[t], b2 = red[16 + t], c2 = red[32 + t], d2 = red[48 + t];
    float4 s;
    s.x = a.x + b2.x + c2.x + d2.x; s.y = a.y + b2.y + c2.y + d2.y;
    s.z = a.z + b2.z + c2.z + d2.z; s.w = a.w + b2.w + c2.w + d2.w;
    msum4[(size_t)n * 16384 + (size_t)h * 64 + (w0 >> 2) + t] = s;
  }
}

// K_conv: implicit-GEMM 3x3 conv, 128px x 128co per block, 4 waves, 16x16x32 bf16 MFMA.
// ratio/updc computed in-kernel from msum. Output: blob in NCHW bf16 (transposed in LDS).
__global__ __launch_bounds__(256) void k_conv(
    const unsigned short* __restrict__ xm, const unsigned short* __restrict__ Wb,
    const float* __restrict__ msum, const float* __restrict__ bias,
    unsigned short* __restrict__ blob, float* __restrict__ psum, float* __restrict__ psq) {
  __shared__ __align__(16) char lds[51472];  // 49920 staging (reused as tile) + lr/lu/cs
  int b = blockIdx.x;
  // XCD swizzle: each XCD owns one image n, h-contiguous -> row reuse in its L2
  int work = (b & 7) * 512 + (b >> 3);
  int wt = work & 1, h = (work >> 1) & 255, n = work >> 9;
  int w0 = wt * 128;
  int t = threadIdx.x;
  int lane = t & 63, wave = t >> 6;
  float* lr = (float*)(lds + 49920);   // ratio*clip per px (128)
  float* lu = (float*)(lds + 50432);   // clip(update) per px (128)
  float* cs = (float*)(lds + 50944);   // column sums (130)
  // stage 3 padded rows x 130 px x 64ch = 3120 16B chunks, swizzled source addr
#pragma unroll
  for (int iter = 0; iter < 12; ++iter) {
    int c = iter * 256 + t;
    int r = (c >= 2080) ? 2 : (c >= 1040 ? 1 : 0);
    int cc = c - r * 1040;
    int wslot = cc >> 3, sub = cc & 7;
    int srcc = (wslot << 3) + (sub ^ (wslot & 7));
    const unsigned short* g = xm + (((size_t)n * HP + h + r) * WP + w0) * CI + (size_t)srcc * 8;
    u32 ldsoff = (u32)(r * 16640 + (((iter * 256 + (wave << 6)) - r * 1040) << 4));
    __builtin_amdgcn_global_load_lds((const __attribute__((address_space(1))) u32*)g,
        (__attribute__((address_space(3))) u32*)(void*)(lds + ldsoff), 16, 0, 0);
  }
  if (t < 48) {   // tail: chunks 3072..3119 (all r=2)
    int c = 3072 + t;
    int cc = c - 2080;
    int wslot = cc >> 3, sub = cc & 7;
    int srcc = (wslot << 3) + (sub ^ (wslot & 7));
    const unsigned short* g = xm + (((size_t)n * HP + h + 2) * WP + w0) * CI + (size_t)srcc * 8;
    u32 ldsoff = (u32)(2 * 16640 + ((3072 - 2080) << 4));
    __builtin_amdgcn_global_load_lds((const __attribute__((address_space(1))) u32*)g,
        (__attribute__((address_space(3))) u32*)(void*)(lds + ldsoff), 16, 0, 0);
  }
  // column sums of mask-count for this strip (w0-1 .. w0+128)
  if (t < 130) {
    int w = w0 - 1 + t;
    float s = 0.f;
    if ((unsigned)w < 256u) {
      const float* mcol = msum + (size_t)n * 65536 + w;
      if (h >= 1) s += mcol[(h - 1) * 256];
      s += mcol[h * 256];
      if (h < 255) s += mcol[(h + 1) * 256];
    }
    cs[t] = s;
  }
  __syncthreads();
  if (t < 128) {
    float s = cs[t] + cs[t + 1] + cs[t + 2];
    float uc = fminf(s, 1.0f);
    lu[t] = uc;
    lr[t] = SLIDE / (s + 1e-6f) * uc;
  }

  int wm = wave >> 1, wn = wave & 1;
  int l15 = lane & 15, l4 = lane >> 4;
  f32x4 zero = {0.f, 0.f, 0.f, 0.f};
  f32x4 acc[4][4];
#pragma unroll
  for (int i = 0; i < 4; ++i)
#pragma unroll
    for (int j = 0; j < 4; ++j) acc[i][j] = zero;

#pragma unroll
  for (int kh = 0; kh < 3; ++kh) {
#pragma unroll
    for (int kw = 0; kw < 3; ++kw) {
      const unsigned short* wtap = Wb + ((kh * 3 + kw) * CO + wn * 64) * CI;
#pragma unroll
      for (int ks = 0; ks < 2; ++ks) {
        bf16x8 af[4], bfr[4];
#pragma unroll
        for (int mf = 0; mf < 4; ++mf) {
          int wslot = wm * 64 + mf * 16 + l15 + kw;
          int baddr = (((kh * 130 + wslot) << 7) + ks * 64 + l4 * 16) ^ ((wslot & 7) << 4);
          af[mf] = *(const bf16x8*)(lds + baddr);
        }
#pragma unroll
        for (int nf = 0; nf < 4; ++nf)
          bfr[nf] = *(const bf16x8*)(wtap + (nf * 16 + l15) * CI + ks * 32 + l4 * 8);
#pragma unroll
        for (int mf = 0; mf < 4; ++mf)
#pragma unroll
          for (int nf = 0; nf < 4; ++nf)
            acc[mf][nf] = __builtin_amdgcn_mfma_f32_16x16x32_bf16(af[mf], bfr[nf], acc[mf][nf], 0, 0, 0);
      }
    }
  }
  __syncthreads();   // staging area free; reuse as co-major output tile [co][128px]

  float bv[4];
#pragma unroll
  for (int nf = 0; nf < 4; ++nf) bv[nf] = bias[wn * 64 + nf * 16 + l15];
  float rs_s[4] = {0.f, 0.f, 0.f, 0.f}, rq_s[4] = {0.f, 0.f, 0.f, 0.f};
  int px0 = wm * 64 + l4 * 4;    // r2 packs 4 consecutive px
#pragma unroll
  for (int mf = 0; mf < 4; ++mf) {
    int pxb = px0 + mf * 16;
    float rs0 = lr[pxb], rs1 = lr[pxb + 1], rs2 = lr[pxb + 2], rs3 = lr[pxb + 3];
    float uc0 = lu[pxb], uc1 = lu[pxb + 1], uc2 = lu[pxb + 2], uc3 = lu[pxb + 3];
#pragma unroll
    for (int nf = 0; nf < 4; ++nf) {
      int co = wn * 64 + nf * 16 + l15;
      float v0 = acc[mf][nf][0] * rs0 + bv[nf] * uc0;
      float v1 = acc[mf][nf][1] * rs1 + bv[nf] * uc1;
      float v2 = acc[mf][nf][2] * rs2 + bv[nf] * uc2;
      float v3 = acc[mf][nf][3] * rs3 + bv[nf] * uc3;
      unsigned short h0 = f2bf(v0), h1 = f2bf(v1), h2 = f2bf(v2), h3 = f2bf(v3);
      float w0f = bf2f(h0), w1f = bf2f(h1), w2f = bf2f(h2), w3f = bf2f(h3);
      rs_s[nf] += w0f + w1f + w2f + w3f;
      rq_s[nf] += w0f * w0f + w1f * w1f + w2f * w2f + w3f * w3f;
      u32 lo = (u32)h0 | ((u32)h1 << 16);
      u32 hi = (u32)h2 | ((u32)h3 << 16);
      *(uint2*)(lds + co * 272 + pxb * 2) = make_uint2(lo, hi);
    }
  }
  float* sred = (float*)(lds + 34816);   // 512 floats (above tile's 34816 B)
#pragma unroll
  for (int nf = 0; nf < 4; ++nf) {
    float s = rs_s[nf], q = rq_s[nf];
    s += __shfl_xor(s, 16); s += __shfl_xor(s, 32);
    q += __shfl_xor(q, 16); q += __shfl_xor(q, 32);
    if (l4 == 0) {
      sred[(wave * 4 + nf) * 16 + l15] = s;
      sred[256 + (wave * 4 + nf) * 16 + l15] = q;
    }
  }
  __syncthreads();
  // blob store: NCHW bf16, 256B contiguous per 16 lanes
  int pixrow = (n * CO) << 16;
#pragma unroll
  for (int iter = 0; iter < 8; ++iter) {
    int i = iter * 256 + t;
    int co = i >> 4, oct = i & 15;
    u16x8 v = *(const u16x8*)(lds + co * 272 + oct * 16);
    *(u16x8*)(blob + (size_t)(pixrow + (co << 16) + (h << 8) + w0 + oct * 8)) = v;
  }
  int co = t & 127;
  int wn2 = co >> 6, nf2 = (co >> 4) & 3, cc2 = co & 15;
  float a0 = sred[(wn2 * 4 + nf2) * 16 + cc2] + sred[((2 + wn2) * 4 + nf2) * 16 + cc2];
  float a1 = sred[256 + (wn2 * 4 + nf2) * 16 + cc2] + sred[256 + ((2 + wn2) * 4 + nf2) * 16 + cc2];
  if (t < 128) psum[(size_t)b * 128 + co] = a0;
  else         psq[(size_t)b * 128 + co]  = a1;
}

// K_bnstats: reduce partials -> bn scale/shift
__global__ void k_bnstats(const float* __restrict__ psum, const float* __restrict__ psq,
                          const float* __restrict__ gamma, const float* __restrict__ beta,
                          float* __restrict__ bn_scale, float* __restrict__ bn_shift) {
  int co = blockIdx.x;
  int t = threadIdx.x;
  float s = 0.f, q = 0.f;
  for (int i = t; i < 4096; i += 256) {
    s += psum[(size_t)i * 128 + co];
    q += psq[(size_t)i * 128 + co];
  }
#pragma unroll
  for (int o = 1; o < 64; o <<= 1) { s += __shfl_xor(s, o); q += __shfl_xor(q, o); }
  __shared__ float red[8];
  int wv = t >> 6, ln = t & 63;
  if (ln == 0) { red[wv] = s; red[4 + wv] = q; }
  __syncthreads();
  if (t == 0) {
    s = red[0] + red[1] + red[2] + red[3];
    q = red[4] + red[5] + red[6] + red[7];
    const float inv = 1.0f / 524288.0f;
    float mean = s * inv;
    float var = q * inv - mean * mean;
    float sc = gamma[co] * rsqrtf(var + 1e-5f);
    bn_scale[co] = sc;
    bn_shift[co] = beta[co] - mean * sc;
  }
}

// K_out: pure streaming. Block = (n,h) row: updc row from msum in LDS, then
// blob (NCHW bf16) -> BN+ReLU -> out (f32 NCHW, nt) and upd broadcast (nt).
// Store shape: 4 px = 16 B per lane per instruction (lane-contiguous 1 KB/wave) —
// do NOT give a lane more px; strided NT stores double HBM write traffic (r6/r7 lesson).
__global__ __launch_bounds__(256) void k_out(const unsigned short* __restrict__ blob,
                                             const float* __restrict__ msum,
                                             const float* __restrict__ bn_scale,
                                             const float* __restrict__ bn_shift,
                                             float* __restrict__ out,
                                             float* __restrict__ upd) {
  __shared__ float lu[256];
  __shared__ float cs[258];
  int b = blockIdx.x;
  int h = b & 255, n = b >> 8;
  int t = threadIdx.x;
  if (t < 258) {
    int w = t - 1;
    float s = 0.f;
    if ((unsigned)w < 256u) {
      const float* mcol = msum + (size_t)n * 65536 + w;
      if (h >= 1) s += mcol[(h - 1) * 256];
      s += mcol[h * 256];
      if (h < 255) s += mcol[(h + 1) * 256];
    }
    cs[t] = s;
  }
  __syncthreads();
  if (t < 256) lu[t] = fminf(cs[t] + cs[t + 1] + cs[t + 2], 1.0f);
  __syncthreads();
  size_t rowbase = ((size_t)(n * CO) << 16) + (h << 8);
#pragma unroll
  for (int iter = 0; iter < 32; ++iter) {
    int i = iter * 256 + t;               // 8192 = 128 c * 64 quads
    int c = i >> 6, q = i & 63;
    size_t off = rowbase + ((size_t)c << 16) + q * 4;
    uint2 raw = *(const uint2*)(blob + off);
    float sc = bn_scale[c], sh = bn_shift[c];
    f32x4 v;
    v.x = fmaxf(bf2f((unsigned short)(raw.x & 0xFFFF)) * sc + sh, 0.f);
    v.y = fmaxf(bf2f((unsigned short)(raw.x >> 16)) * sc + sh, 0.f);
    v.z = fmaxf(bf2f((unsigned short)(raw.y & 0xFFFF)) * sc + sh, 0.f);
    v.w = fmaxf(bf2f((unsigned short)(raw.y >> 16)) * sc + sh, 0.f);
    __builtin_nontemporal_store(v, (f32x4*)(out + off));
    f32x4 uv = *(const f32x4*)&lu[q * 4];
    __builtin_nontemporal_store(uv, (f32x4*)(upd + off));
  }
}

extern "C" void kernel_launch(void* const* d_in, const int* in_sizes, int n_in,
                              void* d_out, int out_size, void* d_ws, size_t ws_size,
                              hipStream_t stream) {
  (void)in_sizes; (void)n_in; (void)out_size; (void)ws_size;
  const float* x     = (const float*)d_in[0];
  const float* mask  = (const float*)d_in[1];
  const float* W     = (const float*)d_in[2];
  const float* bias  = (const float*)d_in[3];
  const float* gamma = (const float*)d_in[4];
  const float* beta  = (const float*)d_in[5];

  float* out = (float*)d_out;                // output 0: 64M f32
  float* upd_out = out + 67108864;           // output 1: 64M f32

  char* wsb = (char*)d_ws;
  unsigned short* Wb = (unsigned short*)wsb;                    // 147,456 B
  float* msum     = (float*)(wsb + (2u << 20));                 // 2 MB
  float* bn_scale = (float*)(wsb + (8u << 20));                 // 512 B
  float* bn_shift = bn_scale + 128;
  float* part_sum = (float*)(wsb + (9u << 20));                 // 2 MB
  float* part_sq  = (float*)(wsb + (11u << 20));                // 2 MB
  unsigned short* xm   = (unsigned short*)(wsb + (16u << 20));  // 65 MB padded NHWC bf16
  unsigned short* blob = (unsigned short*)(wsb + (96u << 20));  // 128 MB NCHW bf16

  k_xm<<<8513, 256, 0, stream>>>((const f32x4*)x, (const f32x4*)mask, xm,
                                 (float4*)msum, W, Wb);
  k_conv<<<4096, 256, 0, stream>>>(xm, Wb, msum, bias, blob, part_sum, part_sq);
  k_bnstats<<<128, 256, 0, stream>>>(part_sum, part_sq, gamma, beta, bn_scale, bn_shift);
  k_out<<<2048, 256, 0, stream>>>(blob, msum, bn_scale, bn_shift, out, upd_out);
}

// Round 9
// 342.313 us; speedup vs baseline: 1.3343x; 1.0034x over previous
//
#include <hip/hip_runtime.h>

typedef __attribute__((ext_vector_type(8))) short bf16x8;
typedef __attribute__((ext_vector_type(8))) unsigned short u16x8;
typedef __attribute__((ext_vector_type(4))) float f32x4;
typedef unsigned int u32;

#define CI 64
#define CO 128
#define HH 256
#define WW 256
#define HP 258
#define WP 258
#define SLIDE 576.0f

__device__ __forceinline__ unsigned short f2bf(float f) {
  union { float f; unsigned int u; } c; c.f = f;
  unsigned int u = c.u;
  return (unsigned short)((u + 0x7FFFu + ((u >> 16) & 1u)) >> 16);
}
__device__ __forceinline__ float bf2f(unsigned short h) {
  union { unsigned int u; float f; } c; c.u = ((unsigned int)h) << 16;
  return c.f;
}

// K_xm: blocks <8192: xm = bf16(x*mask) -> padded NHWC via LDS transpose; msum = sum_ci mask.
//       blocks >=8192: W -> Wb [kh][kw][co][ci] bf16 transpose, and xm border zeroing.
__global__ __launch_bounds__(256) void k_xm(const f32x4* __restrict__ x4,
                                            const f32x4* __restrict__ m4,
                                            unsigned short* __restrict__ xm,
                                            float4* __restrict__ msum4,
                                            const float* __restrict__ W,
                                            unsigned short* __restrict__ Wb) {
  __shared__ __align__(16) float tile[64 * 64 + 256];   // 16 KB tile + 1 KB reduce
  int b = blockIdx.x;
  int t = threadIdx.x;
  if (b >= 8192) {
    int blk = b - 8192;
    if (blk < 288) {
      int i = blk * 256 + t;            // exactly 9*128*64 = 73728
      int ci = i & 63, co = (i >> 6) & 127, tap = i >> 13;
      int kh = tap / 3, kw = tap - 3 * (tap / 3);
      Wb[i] = f2bf(W[((co * CI + ci) * 3 + kh) * 3 + kw]);
    } else {
      int i = (blk - 288) * 256 + t;    // 8 n * 1028 border pixels
      if (i >= 8 * 1028) return;
      int n = i / 1028, p = i - n * 1028;
      int hh, wp;
      if (p < 258) { hh = 0; wp = p; }
      else if (p < 516) { hh = 257; wp = p - 258; }
      else { int q = p - 516; hh = 1 + (q >> 1); wp = (q & 1) * 257; }
      u16x8 z = {0, 0, 0, 0, 0, 0, 0, 0};
      unsigned short* d = xm + (((size_t)n * HP + hh) * WP + wp) * CI;
#pragma unroll
      for (int k = 0; k < 8; ++k) *(u16x8*)(d + k * 8) = z;
    }
    return;
  }
  int wt = b & 3, h = (b >> 2) & 255, n = b >> 10;
  int w0 = wt * 64;
  int p4 = t & 15, chg = t >> 4;                         // px-quad, ch-group(4)
  size_t base = (size_t)n * CI * 16384 + (size_t)h * 64 + (w0 >> 2) + p4;
  float msx = 0.f, msy = 0.f, msz = 0.f, msw = 0.f;
#pragma unroll
  for (int j = 0; j < 4; ++j) {
    int ch = chg * 4 + j;
    size_t o = base + (size_t)ch * 16384;
    f32x4 xv = __builtin_nontemporal_load(&x4[o]);
    f32x4 mv = __builtin_nontemporal_load(&m4[o]);
    msx += mv.x; msy += mv.y; msz += mv.z; msw += mv.w;
    f32x4 pr = xv * mv;
    int kk = (ch >> 3) & 3;                              // XOR key (bits 2-3 of px idx)
    *(f32x4*)&tile[ch * 64 + ((p4 * 4) ^ (kk << 2))] = pr;
  }
  msx += __shfl_xor(msx, 16); msy += __shfl_xor(msy, 16);
  msz += __shfl_xor(msz, 16); msw += __shfl_xor(msw, 16);
  msx += __shfl_xor(msx, 32); msy += __shfl_xor(msy, 32);
  msz += __shfl_xor(msz, 32); msw += __shfl_xor(msw, 32);
  int wave = t >> 6, lane = t & 63;
  float4* red = (float4*)&tile[4096];
  if (lane < 16) red[wave * 16 + lane] = make_float4(msx, msy, msz, msw);
  __syncthreads();
  size_t dstb = (((size_t)n * HP + h + 1) * WP + (w0 + 1)) * CI;
#pragma unroll
  for (int iter = 0; iter < 2; ++iter) {
    int c = iter * 256 + t;
    int px = c >> 3, cg = c & 7;
    u16x8 v;
#pragma unroll
    for (int e = 0; e < 8; ++e) {
      int ch = cg * 8 + e;
      int kk = (ch >> 3) & 3;
      v[e] = f2bf(tile[ch * 64 + (px ^ (kk << 2))]);
    }
    *(u16x8*)(xm + dstb + (size_t)px * CI + cg * 8) = v;
  }
  if (t < 16) {
    float4 a = red[t], b2 = red[16 + t], c2 = red[32 + t], d2 = red[48 + t];
    float4 s;
    s.x = a.x + b2.x + c2.x + d2.x; s.y = a.y + b2.y + c2.y + d2.y;
    s.z = a.z + b2.z + c2.z + d2.z; s.w = a.w + b2.w + c2.w + d2.w;
    msum4[(size_t)n * 16384 + (size_t)h * 64 + (w0 >> 2) + t] = s;
  }
}

// K_conv: implicit-GEMM 3x3 conv, 128px x 128co per block.
// 512 threads / 8 waves: wave = (wm 0..1, wn 0..3) -> 64px x 32co, acc 4x2 fragments.
// Same LDS layout / staging / memory shapes as the proven 4-wave version; this
// probe only raises per-SIMD wave count (3 -> 6) for K-loop latency hiding.
__global__ __launch_bounds__(512) void k_conv(
    const unsigned short* __restrict__ xm, const unsigned short* __restrict__ Wb,
    const float* __restrict__ msum, const float* __restrict__ bias,
    unsigned short* __restrict__ blob, float* __restrict__ psum, float* __restrict__ psq) {
  __shared__ __align__(16) char lds[51472];  // 49920 staging (reused as tile) + lr/lu/cs
  int b = blockIdx.x;
  // XCD swizzle: each XCD owns one image n, h-contiguous -> row reuse in its L2
  int work = (b & 7) * 512 + (b >> 3);
  int wt = work & 1, h = (work >> 1) & 255, n = work >> 9;
  int w0 = wt * 128;
  int t = threadIdx.x;
  int lane = t & 63, wave = t >> 6;
  float* lr = (float*)(lds + 49920);   // ratio*clip per px (128)
  float* lu = (float*)(lds + 50432);   // clip(update) per px (128)
  float* cs = (float*)(lds + 50944);   // column sums (130)
  // stage 3 padded rows x 130 px x 64ch = 3120 16B chunks; LDS linear in chunk idx
#pragma unroll
  for (int iter = 0; iter < 6; ++iter) {
    int c = iter * 512 + t;
    int r = (c >= 2080) ? 2 : (c >= 1040 ? 1 : 0);
    int cc = c - r * 1040;
    int wslot = cc >> 3, sub = cc & 7;
    int srcc = (wslot << 3) + (sub ^ (wslot & 7));
    const unsigned short* g = xm + (((size_t)n * HP + h + r) * WP + w0) * CI + (size_t)srcc * 8;
    u32 ldsoff = (u32)((iter * 512 + (wave << 6)) << 4);
    __builtin_amdgcn_global_load_lds((const __attribute__((address_space(1))) u32*)g,
        (__attribute__((address_space(3))) u32*)(void*)(lds + ldsoff), 16, 0, 0);
  }
  if (t < 48) {   // tail: chunks 3072..3119 (all r=2)
    int c = 3072 + t;
    int cc = c - 2080;
    int wslot = cc >> 3, sub = cc & 7;
    int srcc = (wslot << 3) + (sub ^ (wslot & 7));
    const unsigned short* g = xm + (((size_t)n * HP + h + 2) * WP + w0) * CI + (size_t)srcc * 8;
    u32 ldsoff = (u32)(3072 << 4);
    __builtin_amdgcn_global_load_lds((const __attribute__((address_space(1))) u32*)g,
        (__attribute__((address_space(3))) u32*)(void*)(lds + ldsoff), 16, 0, 0);
  }
  // column sums of mask-count for this strip (w0-1 .. w0+128)
  if (t < 130) {
    int w = w0 - 1 + t;
    float s = 0.f;
    if ((unsigned)w < 256u) {
      const float* mcol = msum + (size_t)n * 65536 + w;
      if (h >= 1) s += mcol[(h - 1) * 256];
      s += mcol[h * 256];
      if (h < 255) s += mcol[(h + 1) * 256];
    }
    cs[t] = s;
  }
  __syncthreads();
  if (t < 128) {
    float s = cs[t] + cs[t + 1] + cs[t + 2];
    float uc = fminf(s, 1.0f);
    lu[t] = uc;
    lr[t] = SLIDE / (s + 1e-6f) * uc;
  }

  int wm = wave >> 2, wn = wave & 3;     // wave: 64 px (wm) x 32 co (wn)
  int l15 = lane & 15, l4 = lane >> 4;
  f32x4 zero = {0.f, 0.f, 0.f, 0.f};
  f32x4 acc[4][2];
#pragma unroll
  for (int i = 0; i < 4; ++i)
#pragma unroll
    for (int j = 0; j < 2; ++j) acc[i][j] = zero;

#pragma unroll
  for (int kh = 0; kh < 3; ++kh) {
#pragma unroll
    for (int kw = 0; kw < 3; ++kw) {
      const unsigned short* wtap = Wb + ((kh * 3 + kw) * CO + wn * 32) * CI;
#pragma unroll
      for (int ks = 0; ks < 2; ++ks) {
        bf16x8 af[4], bfr[2];
#pragma unroll
        for (int mf = 0; mf < 4; ++mf) {
          int wslot = wm * 64 + mf * 16 + l15 + kw;
          int baddr = (((kh * 130 + wslot) << 7) + ks * 64 + l4 * 16) ^ ((wslot & 7) << 4);
          af[mf] = *(const bf16x8*)(lds + baddr);
        }
#pragma unroll
        for (int nf = 0; nf < 2; ++nf)
          bfr[nf] = *(const bf16x8*)(wtap + (nf * 16 + l15) * CI + ks * 32 + l4 * 8);
#pragma unroll
        for (int mf = 0; mf < 4; ++mf)
#pragma unroll
          for (int nf = 0; nf < 2; ++nf)
            acc[mf][nf] = __builtin_amdgcn_mfma_f32_16x16x32_bf16(af[mf], bfr[nf], acc[mf][nf], 0, 0, 0);
      }
    }
  }
  __syncthreads();   // staging area free; reuse as co-major output tile [co][128px]

  float bv[2];
#pragma unroll
  for (int nf = 0; nf < 2; ++nf) bv[nf] = bias[wn * 32 + nf * 16 + l15];
  float rs_s[2] = {0.f, 0.f}, rq_s[2] = {0.f, 0.f};
  int px0 = wm * 64 + l4 * 4;    // r2 packs 4 consecutive px
#pragma unroll
  for (int mf = 0; mf < 4; ++mf) {
    int pxb = px0 + mf * 16;
    float rs0 = lr[pxb], rs1 = lr[pxb + 1], rs2 = lr[pxb + 2], rs3 = lr[pxb + 3];
    float uc0 = lu[pxb], uc1 = lu[pxb + 1], uc2 = lu[pxb + 2], uc3 = lu[pxb + 3];
#pragma unroll
    for (int nf = 0; nf < 2; ++nf) {
      int co = wn * 32 + nf * 16 + l15;
      float v0 = acc[mf][nf][0] * rs0 + bv[nf] * uc0;
      float v1 = acc[mf][nf][1] * rs1 + bv[nf] * uc1;
      float v2 = acc[mf][nf][2] * rs2 + bv[nf] * uc2;
      float v3 = acc[mf][nf][3] * rs3 + bv[nf] * uc3;
      unsigned short h0 = f2bf(v0), h1 = f2bf(v1), h2 = f2bf(v2), h3 = f2bf(v3);
      float w0f = bf2f(h0), w1f = bf2f(h1), w2f = bf2f(h2), w3f = bf2f(h3);
      rs_s[nf] += w0f + w1f + w2f + w3f;
      rq_s[nf] += w0f * w0f + w1f * w1f + w2f * w2f + w3f * w3f;
      u32 lo = (u32)h0 | ((u32)h1 << 16);
      u32 hi = (u32)h2 | ((u32)h3 << 16);
      *(uint2*)(lds + co * 272 + (wm << 7) + (mf * 16 + l4 * 4) * 2) = make_uint2(lo, hi);
    }
  }
  float* sred = (float*)(lds + 34816);   // 16 rows x 16 = 256 f sums, +256 sumsq
#pragma unroll
  for (int nf = 0; nf < 2; ++nf) {
    float s = rs_s[nf], q = rq_s[nf];
    s += __shfl_xor(s, 16); s += __shfl_xor(s, 32);
    q += __shfl_xor(q, 16); q += __shfl_xor(q, 32);
    if (l4 == 0) {
      sred[(wave * 2 + nf) * 16 + l15] = s;
      sred[256 + (wave * 2 + nf) * 16 + l15] = q;
    }
  }
  __syncthreads();
  // blob store: NCHW bf16, 256B contiguous per 16 lanes
  int pixrow = (n * CO) << 16;
#pragma unroll
  for (int iter = 0; iter < 4; ++iter) {
    int i = iter * 512 + t;
    int co = i >> 4, oct = i & 15;
    u16x8 v = *(const u16x8*)(lds + co * 272 + oct * 16);
    *(u16x8*)(blob + (size_t)(pixrow + (co << 16) + (h << 8) + w0 + oct * 8)) = v;
  }
  // per-channel partials: sum the wm=0 and wm=1 wave rows for this co
  int co = t & 127;
  int wnq = co >> 5, nf2 = (co >> 4) & 1, cc2 = co & 15;
  int r0 = ((wnq) * 2 + nf2) * 16 + cc2;            // wave wm=0: wave idx = wn
  int r1 = ((4 + wnq) * 2 + nf2) * 16 + cc2;        // wave wm=1: wave idx = 4+wn
  float a0 = sred[r0] + sred[r1];
  float a1 = sred[256 + r0] + sred[256 + r1];
  if (t < 128) psum[(size_t)b * 128 + co] = a0;
  else if (t < 256) psq[(size_t)b * 128 + co] = a1;
}

// K_bnstats: reduce partials -> bn scale/shift
__global__ void k_bnstats(const float* __restrict__ psum, const float* __restrict__ psq,
                          const float* __restrict__ gamma, const float* __restrict__ beta,
                          float* __restrict__ bn_scale, float* __restrict__ bn_shift) {
  int co = blockIdx.x;
  int t = threadIdx.x;
  float s = 0.f, q = 0.f;
  for (int i = t; i < 4096; i += 256) {
    s += psum[(size_t)i * 128 + co];
    q += psq[(size_t)i * 128 + co];
  }
#pragma unroll
  for (int o = 1; o < 64; o <<= 1) { s += __shfl_xor(s, o); q += __shfl_xor(q, o); }
  __shared__ float red[8];
  int wv = t >> 6, ln = t & 63;
  if (ln == 0) { red[wv] = s; red[4 + wv] = q; }
  __syncthreads();
  if (t == 0) {
    s = red[0] + red[1] + red[2] + red[3];
    q = red[4] + red[5] + red[6] + red[7];
    const float inv = 1.0f / 524288.0f;
    float mean = s * inv;
    float var = q * inv - mean * mean;
    float sc = gamma[co] * rsqrtf(var + 1e-5f);
    bn_scale[co] = sc;
    bn_shift[co] = beta[co] - mean * sc;
  }
}

// K_out: pure streaming. Block = (n,h) row: updc row from msum in LDS, then
// blob (NCHW bf16) -> BN+ReLU -> out (f32 NCHW, nt) and upd broadcast (nt).
// Store shape: 4 px = 16 B per lane per instruction (lane-contiguous 1 KB/wave) —
// strided NT stores double HBM write traffic (r6/r7 lesson).
__global__ __launch_bounds__(256) void k_out(const unsigned short* __restrict__ blob,
                                             const float* __restrict__ msum,
                                             const float* __restrict__ bn_scale,
                                             const float* __restrict__ bn_shift,
                                             float* __restrict__ out,
                                             float* __restrict__ upd) {
  __shared__ float lu[256];
  __shared__ float cs[258];
  int b = blockIdx.x;
  int h = b & 255, n = b >> 8;
  int t = threadIdx.x;
  if (t < 258) {
    int w = t - 1;
    float s = 0.f;
    if ((unsigned)w < 256u) {
      const float* mcol = msum + (size_t)n * 65536 + w;
      if (h >= 1) s += mcol[(h - 1) * 256];
      s += mcol[h * 256];
      if (h < 255) s += mcol[(h + 1) * 256];
    }
    cs[t] = s;
  }
  __syncthreads();
  if (t < 256) lu[t] = fminf(cs[t] + cs[t + 1] + cs[t + 2], 1.0f);
  __syncthreads();
  size_t rowbase = ((size_t)(n * CO) << 16) + (h << 8);
#pragma unroll
  for (int iter = 0; iter < 32; ++iter) {
    int i = iter * 256 + t;               // 8192 = 128 c * 64 quads
    int c = i >> 6, q = i & 63;
    size_t off = rowbase + ((size_t)c << 16) + q * 4;
    uint2 raw = *(const uint2*)(blob + off);
    float sc = bn_scale[c], sh = bn_shift[c];
    f32x4 v;
    v.x = fmaxf(bf2f((unsigned short)(raw.x & 0xFFFF)) * sc + sh, 0.f);
    v.y = fmaxf(bf2f((unsigned short)(raw.x >> 16)) * sc + sh, 0.f);
    v.z = fmaxf(bf2f((unsigned short)(raw.y & 0xFFFF)) * sc + sh, 0.f);
    v.w = fmaxf(bf2f((unsigned short)(raw.y >> 16)) * sc + sh, 0.f);
    __builtin_nontemporal_store(v, (f32x4*)(out + off));
    f32x4 uv = *(const f32x4*)&lu[q * 4];
    __builtin_nontemporal_store(uv, (f32x4*)(upd + off));
  }
}

extern "C" void kernel_launch(void* const* d_in, const int* in_sizes, int n_in,
                              void* d_out, int out_size, void* d_ws, size_t ws_size,
                              hipStream_t stream) {
  (void)in_sizes; (void)n_in; (void)out_size; (void)ws_size;
  const float* x     = (const float*)d_in[0];
  const float* mask  = (const float*)d_in[1];
  const float* W     = (const float*)d_in[2];
  const float* bias  = (const float*)d_in[3];
  const float* gamma = (const float*)d_in[4];
  const float* beta  = (const float*)d_in[5];

  float* out = (float*)d_out;                // output 0: 64M f32
  float* upd_out = out + 67108864;           // output 1: 64M f32

  char* wsb = (char*)d_ws;
  unsigned short* Wb = (unsigned short*)wsb;                    // 147,456 B
  float* msum     = (float*)(wsb + (2u << 20));                 // 2 MB
  float* bn_scale = (float*)(wsb + (8u << 20));                 // 512 B
  float* bn_shift = bn_scale + 128;
  float* part_sum = (float*)(wsb + (9u << 20));                 // 2 MB
  float* part_sq  = (float*)(wsb + (11u << 20));                // 2 MB
  unsigned short* xm   = (unsigned short*)(wsb + (16u << 20));  // 65 MB padded NHWC bf16
  unsigned short* blob = (unsigned short*)(wsb + (96u << 20));  // 128 MB NCHW bf16

  k_xm<<<8513, 256, 0, stream>>>((const f32x4*)x, (const f32x4*)mask, xm,
                                 (float4*)msum, W, Wb);
  k_conv<<<4096, 512, 0, stream>>>(xm, Wb, msum, bias, blob, part_sum, part_sq);
  k_bnstats<<<128, 256, 0, stream>>>(part_sum, part_sq, gamma, beta, bn_scale, bn_shift);
  k_out<<<2048, 256, 0, stream>>>(blob, msum, bn_scale, bn_shift, out, upd_out);
}

// Round 10
// 312.844 us; speedup vs baseline: 1.4600x; 1.0942x over previous
//
#include <hip/hip_runtime.h>

typedef __attribute__((ext_vector_type(8))) short bf16x8;
typedef __attribute__((ext_vector_type(8))) unsigned short u16x8;
typedef __attribute__((ext_vector_type(4))) float f32x4;
typedef unsigned int u32;

#define CI 64
#define CO 128
#define HH 256
#define WW 256
#define HP 258
#define WP 258
#define SLIDE 576.0f

__device__ __forceinline__ unsigned short f2bf(float f) {
  union { float f; unsigned int u; } c; c.f = f;
  unsigned int u = c.u;
  return (unsigned short)((u + 0x7FFFu + ((u >> 16) & 1u)) >> 16);
}
__device__ __forceinline__ float bf2f(unsigned short h) {
  union { unsigned int u; float f; } c; c.u = ((unsigned int)h) << 16;
  return c.f;
}

// K_xm: blocks <8192: xm = bf16(x*mask) -> padded NHWC via LDS transpose; msum = sum_ci mask.
//       blocks >=8192: W -> Wb [kh][kw][co][ci] bf16 transpose, and xm border zeroing.
__global__ __launch_bounds__(256) void k_xm(const f32x4* __restrict__ x4,
                                            const f32x4* __restrict__ m4,
                                            unsigned short* __restrict__ xm,
                                            float4* __restrict__ msum4,
                                            const float* __restrict__ W,
                                            unsigned short* __restrict__ Wb) {
  __shared__ __align__(16) float tile[64 * 64 + 256];   // 16 KB tile + 1 KB reduce
  int b = blockIdx.x;
  int t = threadIdx.x;
  if (b >= 8192) {
    int blk = b - 8192;
    if (blk < 288) {
      int i = blk * 256 + t;            // exactly 9*128*64 = 73728
      int ci = i & 63, co = (i >> 6) & 127, tap = i >> 13;
      int kh = tap / 3, kw = tap - 3 * (tap / 3);
      Wb[i] = f2bf(W[((co * CI + ci) * 3 + kh) * 3 + kw]);
    } else {
      int i = (blk - 288) * 256 + t;    // 8 n * 1028 border pixels
      if (i >= 8 * 1028) return;
      int n = i / 1028, p = i - n * 1028;
      int hh, wp;
      if (p < 258) { hh = 0; wp = p; }
      else if (p < 516) { hh = 257; wp = p - 258; }
      else { int q = p - 516; hh = 1 + (q >> 1); wp = (q & 1) * 257; }
      u16x8 z = {0, 0, 0, 0, 0, 0, 0, 0};
      unsigned short* d = xm + (((size_t)n * HP + hh) * WP + wp) * CI;
#pragma unroll
      for (int k = 0; k < 8; ++k) *(u16x8*)(d + k * 8) = z;
    }
    return;
  }
  int wt = b & 3, h = (b >> 2) & 255, n = b >> 10;
  int w0 = wt * 64;
  int p4 = t & 15, chg = t >> 4;                         // px-quad, ch-group(4)
  size_t base = (size_t)n * CI * 16384 + (size_t)h * 64 + (w0 >> 2) + p4;
  float msx = 0.f, msy = 0.f, msz = 0.f, msw = 0.f;
#pragma unroll
  for (int j = 0; j < 4; ++j) {
    int ch = chg * 4 + j;
    size_t o = base + (size_t)ch * 16384;
    f32x4 xv = __builtin_nontemporal_load(&x4[o]);
    f32x4 mv = __builtin_nontemporal_load(&m4[o]);
    msx += mv.x; msy += mv.y; msz += mv.z; msw += mv.w;
    f32x4 pr = xv * mv;
    int kk = (ch >> 3) & 3;                              // XOR key (bits 2-3 of px idx)
    *(f32x4*)&tile[ch * 64 + ((p4 * 4) ^ (kk << 2))] = pr;
  }
  msx += __shfl_xor(msx, 16); msy += __shfl_xor(msy, 16);
  msz += __shfl_xor(msz, 16); msw += __shfl_xor(msw, 16);
  msx += __shfl_xor(msx, 32); msy += __shfl_xor(msy, 32);
  msz += __shfl_xor(msz, 32); msw += __shfl_xor(msw, 32);
  int wave = t >> 6, lane = t & 63;
  float4* red = (float4*)&tile[4096];
  if (lane < 16) red[wave * 16 + lane] = make_float4(msx, msy, msz, msw);
  __syncthreads();
  size_t dstb = (((size_t)n * HP + h + 1) * WP + (w0 + 1)) * CI;
#pragma unroll
  for (int iter = 0; iter < 2; ++iter) {
    int c = iter * 256 + t;
    int px = c >> 3, cg = c & 7;
    u16x8 v;
#pragma unroll
    for (int e = 0; e < 8; ++e) {
      int ch = cg * 8 + e;
      int kk = (ch >> 3) & 3;
      v[e] = f2bf(tile[ch * 64 + (px ^ (kk << 2))]);
    }
    *(u16x8*)(xm + dstb + (size_t)px * CI + cg * 8) = v;
  }
  if (t < 16) {
    float4 a = red[t], b2 = red[16 + t], c2 = red[32 + t], d2 = red[48 + t];
    float4 s;
    s.x = a.x + b2.x + c2.x + d2.x; s.y = a.y + b2.y + c2.y + d2.y;
    s.z = a.z + b2.z + c2.z + d2.z; s.w = a.w + b2.w + c2.w + d2.w;
    msum4[(size_t)n * 16384 + (size_t)h * 64 + (w0 >> 2) + t] = s;
  }
}

// K_conv: implicit-GEMM 3x3 conv, 128px x 128co per block, 512 threads / 8 waves
// (wave = 64px x 32co, acc 4x2). Also writes the upd broadcast planes (NT) for its
// row-strip — k_conv's memory pipe is under-used vs k_out's (r10 rebalance probe).
__global__ __launch_bounds__(512) void k_conv(
    const unsigned short* __restrict__ xm, const unsigned short* __restrict__ Wb,
    const float* __restrict__ msum, const float* __restrict__ bias,
    unsigned short* __restrict__ blob, float* __restrict__ psum, float* __restrict__ psq,
    float* __restrict__ upd) {
  __shared__ __align__(16) char lds[51472];  // 49920 staging (reused as tile) + lr/lu/cs
  int b = blockIdx.x;
  // XCD swizzle: each XCD owns one image n, h-contiguous -> row reuse in its L2
  int work = (b & 7) * 512 + (b >> 3);
  int wt = work & 1, h = (work >> 1) & 255, n = work >> 9;
  int w0 = wt * 128;
  int t = threadIdx.x;
  int lane = t & 63, wave = t >> 6;
  float* lr = (float*)(lds + 49920);   // ratio*clip per px (128)
  float* lu = (float*)(lds + 50432);   // clip(update) per px (128)
  float* cs = (float*)(lds + 50944);   // column sums (130)
  // stage 3 padded rows x 130 px x 64ch = 3120 16B chunks; LDS linear in chunk idx
#pragma unroll
  for (int iter = 0; iter < 6; ++iter) {
    int c = iter * 512 + t;
    int r = (c >= 2080) ? 2 : (c >= 1040 ? 1 : 0);
    int cc = c - r * 1040;
    int wslot = cc >> 3, sub = cc & 7;
    int srcc = (wslot << 3) + (sub ^ (wslot & 7));
    const unsigned short* g = xm + (((size_t)n * HP + h + r) * WP + w0) * CI + (size_t)srcc * 8;
    u32 ldsoff = (u32)((iter * 512 + (wave << 6)) << 4);
    __builtin_amdgcn_global_load_lds((const __attribute__((address_space(1))) u32*)g,
        (__attribute__((address_space(3))) u32*)(void*)(lds + ldsoff), 16, 0, 0);
  }
  if (t < 48) {   // tail: chunks 3072..3119 (all r=2)
    int c = 3072 + t;
    int cc = c - 2080;
    int wslot = cc >> 3, sub = cc & 7;
    int srcc = (wslot << 3) + (sub ^ (wslot & 7));
    const unsigned short* g = xm + (((size_t)n * HP + h + 2) * WP + w0) * CI + (size_t)srcc * 8;
    u32 ldsoff = (u32)(3072 << 4);
    __builtin_amdgcn_global_load_lds((const __attribute__((address_space(1))) u32*)g,
        (__attribute__((address_space(3))) u32*)(void*)(lds + ldsoff), 16, 0, 0);
  }
  // column sums of mask-count for this strip (w0-1 .. w0+128)
  if (t < 130) {
    int w = w0 - 1 + t;
    float s = 0.f;
    if ((unsigned)w < 256u) {
      const float* mcol = msum + (size_t)n * 65536 + w;
      if (h >= 1) s += mcol[(h - 1) * 256];
      s += mcol[h * 256];
      if (h < 255) s += mcol[(h + 1) * 256];
    }
    cs[t] = s;
  }
  __syncthreads();
  if (t < 128) {
    float s = cs[t] + cs[t + 1] + cs[t + 2];
    float uc = fminf(s, 1.0f);
    lu[t] = uc;
    lr[t] = SLIDE / (s + 1e-6f) * uc;
  }

  int wm = wave >> 2, wn = wave & 3;     // wave: 64 px (wm) x 32 co (wn)
  int l15 = lane & 15, l4 = lane >> 4;
  f32x4 zero = {0.f, 0.f, 0.f, 0.f};
  f32x4 acc[4][2];
#pragma unroll
  for (int i = 0; i < 4; ++i)
#pragma unroll
    for (int j = 0; j < 2; ++j) acc[i][j] = zero;

#pragma unroll
  for (int kh = 0; kh < 3; ++kh) {
#pragma unroll
    for (int kw = 0; kw < 3; ++kw) {
      const unsigned short* wtap = Wb + ((kh * 3 + kw) * CO + wn * 32) * CI;
#pragma unroll
      for (int ks = 0; ks < 2; ++ks) {
        bf16x8 af[4], bfr[2];
#pragma unroll
        for (int mf = 0; mf < 4; ++mf) {
          int wslot = wm * 64 + mf * 16 + l15 + kw;
          int baddr = (((kh * 130 + wslot) << 7) + ks * 64 + l4 * 16) ^ ((wslot & 7) << 4);
          af[mf] = *(const bf16x8*)(lds + baddr);
        }
#pragma unroll
        for (int nf = 0; nf < 2; ++nf)
          bfr[nf] = *(const bf16x8*)(wtap + (nf * 16 + l15) * CI + ks * 32 + l4 * 8);
#pragma unroll
        for (int mf = 0; mf < 4; ++mf)
#pragma unroll
          for (int nf = 0; nf < 2; ++nf)
            acc[mf][nf] = __builtin_amdgcn_mfma_f32_16x16x32_bf16(af[mf], bfr[nf], acc[mf][nf], 0, 0, 0);
      }
    }
  }
  __syncthreads();   // staging area free; reuse as co-major output tile [co][128px]

  float bv[2];
#pragma unroll
  for (int nf = 0; nf < 2; ++nf) bv[nf] = bias[wn * 32 + nf * 16 + l15];
  float rs_s[2] = {0.f, 0.f}, rq_s[2] = {0.f, 0.f};
  int px0 = wm * 64 + l4 * 4;    // r2 packs 4 consecutive px
#pragma unroll
  for (int mf = 0; mf < 4; ++mf) {
    int pxb = px0 + mf * 16;
    float rs0 = lr[pxb], rs1 = lr[pxb + 1], rs2 = lr[pxb + 2], rs3 = lr[pxb + 3];
    float uc0 = lu[pxb], uc1 = lu[pxb + 1], uc2 = lu[pxb + 2], uc3 = lu[pxb + 3];
#pragma unroll
    for (int nf = 0; nf < 2; ++nf) {
      int co = wn * 32 + nf * 16 + l15;
      float v0 = acc[mf][nf][0] * rs0 + bv[nf] * uc0;
      float v1 = acc[mf][nf][1] * rs1 + bv[nf] * uc1;
      float v2 = acc[mf][nf][2] * rs2 + bv[nf] * uc2;
      float v3 = acc[mf][nf][3] * rs3 + bv[nf] * uc3;
      unsigned short h0 = f2bf(v0), h1 = f2bf(v1), h2 = f2bf(v2), h3 = f2bf(v3);
      float w0f = bf2f(h0), w1f = bf2f(h1), w2f = bf2f(h2), w3f = bf2f(h3);
      rs_s[nf] += w0f + w1f + w2f + w3f;
      rq_s[nf] += w0f * w0f + w1f * w1f + w2f * w2f + w3f * w3f;
      u32 lo = (u32)h0 | ((u32)h1 << 16);
      u32 hi = (u32)h2 | ((u32)h3 << 16);
      *(uint2*)(lds + co * 272 + (wm << 7) + (mf * 16 + l4 * 4) * 2) = make_uint2(lo, hi);
    }
  }
  float* sred = (float*)(lds + 34816);   // 16 rows x 16 = 256 f sums, +256 sumsq
#pragma unroll
  for (int nf = 0; nf < 2; ++nf) {
    float s = rs_s[nf], q = rq_s[nf];
    s += __shfl_xor(s, 16); s += __shfl_xor(s, 32);
    q += __shfl_xor(q, 16); q += __shfl_xor(q, 32);
    if (l4 == 0) {
      sred[(wave * 2 + nf) * 16 + l15] = s;
      sred[256 + (wave * 2 + nf) * 16 + l15] = q;
    }
  }
  __syncthreads();
  // blob store: NCHW bf16, 256B contiguous per 16 lanes
  int pixrow = (n * CO) << 16;
#pragma unroll
  for (int iter = 0; iter < 4; ++iter) {
    int i = iter * 512 + t;
    int co = i >> 4, oct = i & 15;
    u16x8 v = *(const u16x8*)(lds + co * 272 + oct * 16);
    *(u16x8*)(blob + (size_t)(pixrow + (co << 16) + (h << 8) + w0 + oct * 8)) = v;
  }
  // upd broadcast store: 128 co planes x 128 px, NT, 16B/lane lane-contiguous
  float* updp = upd + (((size_t)(n * CO)) << 16) + (h << 8) + w0;
#pragma unroll
  for (int iter = 0; iter < 8; ++iter) {
    int i = iter * 512 + t;
    int co = i >> 5, seg = i & 31;     // 32 lanes x 4 px cover 128 px
    f32x4 uv = *(const f32x4*)&lu[seg * 4];
    __builtin_nontemporal_store(uv, (f32x4*)(updp + ((size_t)co << 16) + seg * 4));
  }
  // per-channel partials: sum the wm=0 and wm=1 wave rows for this co
  int co = t & 127;
  int wnq = co >> 5, nf2 = (co >> 4) & 1, cc2 = co & 15;
  int r0 = ((wnq) * 2 + nf2) * 16 + cc2;            // wave wm=0: wave idx = wn
  int r1 = ((4 + wnq) * 2 + nf2) * 16 + cc2;        // wave wm=1: wave idx = 4+wn
  float a0 = sred[r0] + sred[r1];
  float a1 = sred[256 + r0] + sred[256 + r1];
  if (t < 128) psum[(size_t)b * 128 + co] = a0;
  else if (t < 256) psq[(size_t)b * 128 + co] = a1;
}

// K_bnstats: reduce partials -> bn scale/shift
__global__ void k_bnstats(const float* __restrict__ psum, const float* __restrict__ psq,
                          const float* __restrict__ gamma, const float* __restrict__ beta,
                          float* __restrict__ bn_scale, float* __restrict__ bn_shift) {
  int co = blockIdx.x;
  int t = threadIdx.x;
  float s = 0.f, q = 0.f;
  for (int i = t; i < 4096; i += 256) {
    s += psum[(size_t)i * 128 + co];
    q += psq[(size_t)i * 128 + co];
  }
#pragma unroll
  for (int o = 1; o < 64; o <<= 1) { s += __shfl_xor(s, o); q += __shfl_xor(q, o); }
  __shared__ float red[8];
  int wv = t >> 6, ln = t & 63;
  if (ln == 0) { red[wv] = s; red[4 + wv] = q; }
  __syncthreads();
  if (t == 0) {
    s = red[0] + red[1] + red[2] + red[3];
    q = red[4] + red[5] + red[6] + red[7];
    const float inv = 1.0f / 524288.0f;
    float mean = s * inv;
    float var = q * inv - mean * mean;
    float sc = gamma[co] * rsqrtf(var + 1e-5f);
    bn_scale[co] = sc;
    bn_shift[co] = beta[co] - mean * sc;
  }
}

// K_out: pure streaming. blob (NCHW bf16) -> BN+ReLU -> out (f32 NCHW, nt).
// upd is written by k_conv now. Store shape: 16B/lane lane-contiguous (r6/r7 lesson).
__global__ __launch_bounds__(256) void k_out(const unsigned short* __restrict__ blob,
                                             const float* __restrict__ bn_scale,
                                             const float* __restrict__ bn_shift,
                                             float* __restrict__ out) {
  int b = blockIdx.x;
  int h = b & 255, n = b >> 8;
  int t = threadIdx.x;
  size_t rowbase = ((size_t)(n * CO) << 16) + (h << 8);
#pragma unroll
  for (int iter = 0; iter < 32; ++iter) {
    int i = iter * 256 + t;               // 8192 = 128 c * 64 quads
    int c = i >> 6, q = i & 63;
    size_t off = rowbase + ((size_t)c << 16) + q * 4;
    uint2 raw = *(const uint2*)(blob + off);
    float sc = bn_scale[c], sh = bn_shift[c];
    f32x4 v;
    v.x = fmaxf(bf2f((unsigned short)(raw.x & 0xFFFF)) * sc + sh, 0.f);
    v.y = fmaxf(bf2f((unsigned short)(raw.x >> 16)) * sc + sh, 0.f);
    v.z = fmaxf(bf2f((unsigned short)(raw.y & 0xFFFF)) * sc + sh, 0.f);
    v.w = fmaxf(bf2f((unsigned short)(raw.y >> 16)) * sc + sh, 0.f);
    __builtin_nontemporal_store(v, (f32x4*)(out + off));
  }
}

extern "C" void kernel_launch(void* const* d_in, const int* in_sizes, int n_in,
                              void* d_out, int out_size, void* d_ws, size_t ws_size,
                              hipStream_t stream) {
  (void)in_sizes; (void)n_in; (void)out_size; (void)ws_size;
  const float* x     = (const float*)d_in[0];
  const float* mask  = (const float*)d_in[1];
  const float* W     = (const float*)d_in[2];
  const float* bias  = (const float*)d_in[3];
  const float* gamma = (const float*)d_in[4];
  const float* beta  = (const float*)d_in[5];

  float* out = (float*)d_out;                // output 0: 64M f32
  float* upd_out = out + 67108864;           // output 1: 64M f32

  char* wsb = (char*)d_ws;
  unsigned short* Wb = (unsigned short*)wsb;                    // 147,456 B
  float* msum     = (float*)(wsb + (2u << 20));                 // 2 MB
  float* bn_scale = (float*)(wsb + (8u << 20));                 // 512 B
  float* bn_shift = bn_scale + 128;
  float* part_sum = (float*)(wsb + (9u << 20));                 // 2 MB
  float* part_sq  = (float*)(wsb + (11u << 20));                // 2 MB
  unsigned short* xm   = (unsigned short*)(wsb + (16u << 20));  // 65 MB padded NHWC bf16
  unsigned short* blob = (unsigned short*)(wsb + (96u << 20));  // 128 MB NCHW bf16

  k_xm<<<8513, 256, 0, stream>>>((const f32x4*)x, (const f32x4*)mask, xm,
                                 (float4*)msum, W, Wb);
  k_conv<<<4096, 512, 0, stream>>>(xm, Wb, msum, bias, blob, part_sum, part_sq, upd_out);
  k_bnstats<<<128, 256, 0, stream>>>(part_sum, part_sq, gamma, beta, bn_scale, bn_shift);
  k_out<<<2048, 256, 0, stream>>>(blob, bn_scale, bn_shift, out);
}